// Round 1
// baseline (506.760 us; speedup 1.0000x reference)
//
#include <hip/hip_runtime.h>
#include <math.h>

#define T 2048
#define HID 4096
#define NH 32
#define NKV 8
#define HD 128
#define QSCALE 0.08838834764831845f   // 1/sqrt(128)

typedef __attribute__((ext_vector_type(8))) short short8;
typedef __attribute__((ext_vector_type(4))) float f32x4;
typedef __attribute__((ext_vector_type(16))) float f32x16;

static __device__ __forceinline__ unsigned short f2bf(float f) {
  union { float f; unsigned u; } v; v.f = f;
  unsigned r = v.u;
  r += 0x7fffu + ((r >> 16) & 1u);   // round-to-nearest-even
  return (unsigned short)(r >> 16);
}

// async 16B/lane global->LDS DMA; LDS dest is wave-uniform base + lane*16
static __device__ __forceinline__ void async_cp16(const unsigned short* g, unsigned short* l) {
  __builtin_amdgcn_global_load_lds(
      (const __attribute__((address_space(1))) void*)g,
      (__attribute__((address_space(3))) void*)l,
      16, 0, 0);
}

// ---------------- fused cast fp32 -> bf16 for x, Wq, Wk, Wv ----------------
__global__ __launch_bounds__(256) void cast4_kernel(const float* __restrict__ s0, const float* __restrict__ s1,
                                                    const float* __restrict__ s2, const float* __restrict__ s3,
                                                    unsigned short* __restrict__ d0, unsigned short* __restrict__ d1,
                                                    unsigned short* __restrict__ d2, unsigned short* __restrict__ d3,
                                                    int n0, int n1, int n2, int n3) {
  int i = blockIdx.x * 256 + threadIdx.x;
  const float* s; unsigned short* d; int j = i;
  if (j < n0) { s = s0; d = d0; }
  else { j -= n0;
    if (j < n1) { s = s1; d = d1; }
    else { j -= n1;
      if (j < n2) { s = s2; d = d2; }
      else { j -= n2;
        if (j >= n3) return;
        s = s3; d = d3; } } }
  float4 f = ((const float4*)s)[j];
  ushort4 o;
  o.x = f2bf(f.x); o.y = f2bf(f.y); o.z = f2bf(f.z); o.w = f2bf(f.w);
  ((ushort4*)d)[j] = o;
}

__global__ __launch_bounds__(256) void cast_bf16_kernel(const float* __restrict__ src,
                                                        unsigned short* __restrict__ dst,
                                                        int n4) {
  int i = blockIdx.x * 256 + threadIdx.x;
  if (i >= n4) return;
  float4 f = ((const float4*)src)[i];
  ushort4 o;
  o.x = f2bf(f.x); o.y = f2bf(f.y); o.z = f2bf(f.z); o.w = f2bf(f.w);
  ((ushort4*)dst)[i] = o;
}

// ---------------- 8-phase 256x256 GEMM (T2+T3+T4+T5 template) ----------------
// C[M,N] fp32 = A[M,K]bf16 * Bt[N,K]bf16^T.
// 512 threads = 8 waves (2M x 4N), per-wave 128x64 output, 16x16x32 MFMA.
// BK=64, 2-tile double-buffered LDS (128 KiB), one 128x64 half-tile staged
// per phase via global_load_lds w16 (linear dest, pre-swizzled source),
// counted vmcnt(4) only at phases 4/8 (never 0 in the loop).
// Swizzle: 16B slot ^= (row&7) on both the global source and the ds_read.

static __device__ __forceinline__ short8 ldfrag(const unsigned short* tile, int row0, int ks, int lane) {
  // logical k-slot = ks*4 + (lane>>4); row0 is a multiple of 16 so row&7 == lane&7
  int row = row0 + (lane & 15);
  int slot = (ks * 4 + (lane >> 4)) ^ (lane & 7);
  return *(const short8*)&tile[row * 64 + slot * 8];
}

static __device__ __forceinline__ void stage_half(const unsigned short* __restrict__ G, long grow0, int K, int k0,
                                                  unsigned short* lds, int h, int wave, int lane) {
#pragma unroll
  for (int i = 0; i < 2; i++) {
    long row = grow0 + h * 128 + i * 64 + wave * 8 + (lane >> 3);
    int slot = (lane & 7) ^ (lane >> 3);       // inverse swizzle on the source
    async_cp16(&G[row * (long)K + k0 + slot * 8], &lds[h * 8192 + i * 4096 + wave * 512]);
  }
}

template <int MQ, int NQ>
static __device__ __forceinline__ void mfma_quad(const short8 (&af)[4][2], const short8 (&bf)[2][2],
                                                 f32x4 (&acc)[8][4]) {
  __builtin_amdgcn_s_setprio(1);
#pragma unroll
  for (int m = 0; m < 4; m++)
#pragma unroll
    for (int n = 0; n < 2; n++)
#pragma unroll
      for (int ks = 0; ks < 2; ks++)
        acc[MQ * 4 + m][NQ * 2 + n] = __builtin_amdgcn_mfma_f32_16x16x32_bf16(
            af[m][ks], bf[n][ks], acc[MQ * 4 + m][NQ * 2 + n], 0, 0, 0);
  __builtin_amdgcn_s_setprio(0);
}

#define SCHED0 __builtin_amdgcn_sched_barrier(0)
#define BAR_PRE  do { SCHED0; __builtin_amdgcn_s_barrier(); \
                      asm volatile("s_waitcnt lgkmcnt(0)" ::: "memory"); SCHED0; } while (0)
#define BAR_POST do { SCHED0; __builtin_amdgcn_s_barrier(); SCHED0; } while (0)

__global__ __launch_bounds__(512, 2) void gemm8(const unsigned short* __restrict__ A,
                                                const unsigned short* __restrict__ Bt,
                                                float* __restrict__ C,
                                                int M, int N, int K) {
  __shared__ __align__(16) unsigned short As[2][16384];   // 2 x 256x64 bf16
  __shared__ __align__(16) unsigned short Bs[2][16384];
  int tid = threadIdx.x, wave = tid >> 6, lane = tid & 63;
  int wm = wave >> 2, wn = wave & 3;
  long bm0 = (long)blockIdx.y * 256, bn0 = (long)blockIdx.x * 256;
  int ar = wm * 128, br = wn * 64;

  f32x4 acc[8][4] = {};
  short8 a0[4][2], a1[4][2], b0[2][2], b1[2][2];

  // ---- prologue: buf0 <- tile0 (all 4 halves), buf1 <- tile1 B halves
  stage_half(Bt, bn0, K, 0, Bs[0], 0, wave, lane);
  stage_half(Bt, bn0, K, 0, Bs[0], 1, wave, lane);
  stage_half(A,  bm0, K, 0, As[0], 0, wave, lane);
  stage_half(A,  bm0, K, 0, As[0], 1, wave, lane);
  stage_half(Bt, bn0, K, 64, Bs[1], 0, wave, lane);
  stage_half(Bt, bn0, K, 64, Bs[1], 1, wave, lane);
  asm volatile("s_waitcnt vmcnt(4)" ::: "memory");   // tile0 landed; tile1-B in flight
  SCHED0; __builtin_amdgcn_s_barrier(); SCHED0;

  int nkt = K >> 6;                 // K-tiles of 64
#pragma unroll 1
  for (int it = 0; it < (nkt >> 1); ++it) {
    int k1 = (2 * it + 1) << 6;
    int t2 = 2 * it + 2; if (t2 > nkt - 1) t2 = nkt - 1;   // tail: re-stage (dead data)
    int t3 = 2 * it + 3; if (t3 > nkt - 1) t3 = nkt - 1;
    int k2 = t2 << 6, k3 = t3 << 6;

    // P0: reads a0,b0 from buf0; stage As[1].h0 <- tile 2it+1
#pragma unroll
    for (int m = 0; m < 4; m++)
#pragma unroll
      for (int ks = 0; ks < 2; ks++) a0[m][ks] = ldfrag(As[0], ar + m * 16, ks, lane);
#pragma unroll
    for (int n = 0; n < 2; n++)
#pragma unroll
      for (int ks = 0; ks < 2; ks++) b0[n][ks] = ldfrag(Bs[0], br + n * 16, ks, lane);
    stage_half(A, bm0, K, k1, As[1], 0, wave, lane);
    BAR_PRE; mfma_quad<0, 0>(a0, b0, acc); BAR_POST;

    // P1: reads b1 from buf0; stage As[1].h1 <- tile 2it+1
#pragma unroll
    for (int n = 0; n < 2; n++)
#pragma unroll
      for (int ks = 0; ks < 2; ks++) b1[n][ks] = ldfrag(Bs[0], br + (2 + n) * 16, ks, lane);
    stage_half(A, bm0, K, k1, As[1], 1, wave, lane);
    BAR_PRE; mfma_quad<0, 1>(a0, b1, acc); BAR_POST;

    // P2: reads a1 from buf0; stage Bs[0].h0 <- tile 2it+2 (buf0 B reads done at P1)
#pragma unroll
    for (int m = 0; m < 4; m++)
#pragma unroll
      for (int ks = 0; ks < 2; ks++) a1[m][ks] = ldfrag(As[0], ar + (4 + m) * 16, ks, lane);
    stage_half(Bt, bn0, K, k2, Bs[0], 0, wave, lane);
    BAR_PRE; mfma_quad<1, 0>(a1, b0, acc); BAR_POST;

    // P3: stage Bs[0].h1; counted vmcnt(4) guarantees tile 2it+1 fully landed
    stage_half(Bt, bn0, K, k2, Bs[0], 1, wave, lane);
    asm volatile("s_waitcnt vmcnt(4)" ::: "memory");
    BAR_PRE; mfma_quad<1, 1>(a1, b1, acc); BAR_POST;

    // P4: reads a0,b0 from buf1; stage As[0].h0 <- tile 2it+2 (buf0 A reads done at P2)
#pragma unroll
    for (int m = 0; m < 4; m++)
#pragma unroll
      for (int ks = 0; ks < 2; ks++) a0[m][ks] = ldfrag(As[1], ar + m * 16, ks, lane);
#pragma unroll
    for (int n = 0; n < 2; n++)
#pragma unroll
      for (int ks = 0; ks < 2; ks++) b0[n][ks] = ldfrag(Bs[1], br + n * 16, ks, lane);
    stage_half(A, bm0, K, k2, As[0], 0, wave, lane);
    BAR_PRE; mfma_quad<0, 0>(a0, b0, acc); BAR_POST;

    // P5: reads b1 from buf1; stage As[0].h1
#pragma unroll
    for (int n = 0; n < 2; n++)
#pragma unroll
      for (int ks = 0; ks < 2; ks++) b1[n][ks] = ldfrag(Bs[1], br + (2 + n) * 16, ks, lane);
    stage_half(A, bm0, K, k2, As[0], 1, wave, lane);
    BAR_PRE; mfma_quad<0, 1>(a0, b1, acc); BAR_POST;

    // P6: reads a1 from buf1; stage Bs[1].h0 <- tile 2it+3 (buf1 B reads done at P5)
#pragma unroll
    for (int m = 0; m < 4; m++)
#pragma unroll
      for (int ks = 0; ks < 2; ks++) a1[m][ks] = ldfrag(As[1], ar + (4 + m) * 16, ks, lane);
    stage_half(Bt, bn0, K, k3, Bs[1], 0, wave, lane);
    BAR_PRE; mfma_quad<1, 0>(a1, b0, acc); BAR_POST;

    // P7: stage Bs[1].h1; counted vmcnt(4) guarantees tile 2it+2 fully landed
    stage_half(Bt, bn0, K, k3, Bs[1], 1, wave, lane);
    asm volatile("s_waitcnt vmcnt(4)" ::: "memory");
    BAR_PRE; mfma_quad<1, 1>(a1, b1, acc); BAR_POST;
  }
  asm volatile("s_waitcnt vmcnt(0)" ::: "memory");   // drain tail stages before endpgm

  // epilogue: 16x16 C/D layout: col = lane&15, row = (lane>>4)*4 + j
#pragma unroll
  for (int m = 0; m < 8; m++)
#pragma unroll
    for (int n = 0; n < 4; n++) {
      long row = bm0 + ar + m * 16 + ((lane >> 4) << 2);
      long col = bn0 + br + n * 16 + (lane & 15);
#pragma unroll
      for (int j = 0; j < 4; j++)
        C[(row + j) * (long)N + col] = acc[m][n][j];
    }
}

// ---------------- RoPE (llama3 scaling) on Q,K from fused QKV; head-major bf16 ----------------
__global__ __launch_bounds__(64) void rope_qk(const float* __restrict__ qkvf,
                                              unsigned short* __restrict__ qb,
                                              unsigned short* __restrict__ kb) {
  int t = blockIdx.x, hh = blockIdx.y, d = threadIdx.x;  // d in [0,64)
  float ex = (float)d * (1.0f / 64.0f);
  float inv = expf(-ex * 13.122363377404328f);           // 500000^(-d/64)
  float wl = 6.283185307179586f / inv;
  float inv_s;
  if (wl > 8192.0f)       inv_s = inv * 0.125f;
  else if (wl < 2048.0f)  inv_s = inv;
  else {
    float smooth = (8192.0f / wl - 1.0f) * (1.0f / 3.0f);
    inv_s = (1.0f - smooth) * 0.125f * inv + smooth * inv;
  }
  float ang = (float)t * inv_s;
  float s, c;
  sincosf(ang, &s, &c);
  if (hh < NH) {
    const float* base = qkvf + (long)t * 6144 + hh * HD;
    float lo = base[d], hi = base[d + 64];
    long o = ((long)hh * T + t) * HD;
    qb[o + d]      = f2bf((lo * c - hi * s) * QSCALE);
    qb[o + d + 64] = f2bf((hi * c + lo * s) * QSCALE);
  } else {
    int h = hh - NH;
    const float* base = qkvf + (long)t * 6144 + 4096 + h * HD;
    float lo = base[d], hi = base[d + 64];
    long o = ((long)h * T + t) * HD;
    kb[o + d]      = f2bf(lo * c - hi * s);
    kb[o + d + 64] = f2bf(hi * c + lo * s);
  }
}

// ---------------- V: qkvf[t][5120 + h*128+d] fp32 -> [h][d][t] bf16 ----------------
__global__ __launch_bounds__(256) void transpose_v(const float* __restrict__ qkvf,
                                                   unsigned short* __restrict__ vtb) {
  __shared__ float tile[64][33];
  int t0 = blockIdx.x * 64, d0 = blockIdx.y * 32, h = blockIdx.z;
  int tid = threadIdx.x;
  int dd = tid & 31, tt = tid >> 5;
#pragma unroll
  for (int i = 0; i < 8; i++) {
    int t = tt + i * 8;
    tile[t][dd] = qkvf[(long)(t0 + t) * 6144 + 5120 + h * HD + d0 + dd];
  }
  __syncthreads();
  int t2 = tid & 63, d2 = tid >> 6;
#pragma unroll
  for (int i = 0; i < 8; i++) {
    int d = d2 + i * 4;
    vtb[((long)(h * HD + d0 + d)) * T + t0 + t2] = f2bf(tile[t2][d]);
  }
}

// ---------------- flash attention, causal, GQA (R3-proven, unchanged) ----------------
__global__ __launch_bounds__(256, 2) void attn_kernel(const unsigned short* __restrict__ qb,
                                                      const unsigned short* __restrict__ kbuf,
                                                      const unsigned short* __restrict__ vtb,
                                                      unsigned short* __restrict__ ob) {
  __shared__ __align__(16) unsigned short Ks[64 * 128];   // [key][d], groups XOR row&15
  __shared__ __align__(16) unsigned short Vs[128 * 64];   // [d][key], groups XOR row&7
  __shared__ __align__(16) unsigned short Ps[4][32 * 76]; // per-wave P, stride 76
  int h = blockIdx.y;
  int kvh = h >> 2;
  // complementary causal workload pairing for co-resident blocks
  int qt = (blockIdx.y >= 16) ? (int)(gridDim.x - 1 - blockIdx.x) : (int)blockIdx.x;
  int q0 = qt * 128;
  int tid = threadIdx.x, wave = tid >> 6, lane = tid & 63;
  int l31 = lane & 31, half = lane >> 5;
  const unsigned short* Kb = kbuf + (long)kvh * T * HD;  // [t][d]
  const unsigned short* Vb = vtb + (long)kvh * HD * T;   // [d][t]

  // Q A-frags (32x32x16 layout: m=lane&31, k=half*8+j)
  int qrow = q0 + wave * 32 + l31;
  short8 aq[8];
#pragma unroll
  for (int ks = 0; ks < 8; ks++)
    aq[ks] = *(const short8*)&qb[((long)h * T + qrow) * HD + ks * 16 + half * 8];

  f32x16 oacc[4] = {};
  float psum[16];
#pragma unroll
  for (int r = 0; r < 16; r++) psum[r] = 0.0f;

  int ntiles = 2 * qt + 2;
  for (int tile = 0; tile < ntiles; tile++) {
    int kb0 = tile * 64;
#pragma unroll
    for (int i = 0; i < 4; i++) {
      int c = wave * 4 + i;
      { int row = c * 4 + (lane >> 4);
        int g = (lane & 15) ^ (row & 15);
        async_cp16(&Kb[(long)(kb0 + row) * HD + g * 8], &Ks[c * 512]); }
      { int row = c * 8 + (lane >> 3);
        int g = (lane & 7) ^ (row & 7);
        async_cp16(&Vb[(long)row * T + kb0 + g * 8], &Vs[c * 512]); }
    }
    __syncthreads();

    // S = Q K^T : 32q x 64key per wave
    f32x16 sacc[2] = {};
#pragma unroll
    for (int ks = 0; ks < 8; ks++)
#pragma unroll
      for (int nt = 0; nt < 2; nt++) {
        int row = nt * 32 + l31;
        short8 bk = *(const short8*)&Ks[row * 128 + (((2 * ks + half) ^ (row & 15)) * 8)];
        sacc[nt] = __builtin_amdgcn_mfma_f32_32x32x16_bf16(aq[ks], bk, sacc[nt], 0, 0, 0);
      }

    // causal mask (wave-uniform branch)
    if (kb0 + 63 > q0 + wave * 32) {
#pragma unroll
      for (int nt = 0; nt < 2; nt++) {
        int key = kb0 + nt * 32 + l31;
#pragma unroll
        for (int r = 0; r < 16; r++) {
          int qr = q0 + wave * 32 + (r & 3) + 8 * (r >> 2) + 4 * half;
          if (key > qr) sacc[nt][r] = -3.0e38f;
        }
      }
    }

    // p = exp(s); per-lane partial row sums; pack P to LDS
#pragma unroll
    for (int nt = 0; nt < 2; nt++)
#pragma unroll
      for (int r = 0; r < 16; r++) {
        float p = __expf(sacc[nt][r]);
        psum[r] += p;
        int prow = (r & 3) + 8 * (r >> 2) + 4 * half;
        Ps[wave][prow * 76 + nt * 32 + l31] = f2bf(p);
      }

    // O += P V
#pragma unroll
    for (int ks = 0; ks < 4; ks++) {
      short8 ap = *(const short8*)&Ps[wave][l31 * 76 + ks * 16 + half * 8];
#pragma unroll
      for (int nt = 0; nt < 4; nt++) {
        int row = nt * 32 + l31;
        short8 bv = *(const short8*)&Vs[row * 64 + (((2 * ks + half) ^ (row & 7)) * 8)];
        oacc[nt] = __builtin_amdgcn_mfma_f32_32x32x16_bf16(ap, bv, oacc[nt], 0, 0, 0);
      }
    }
    __syncthreads();
  }

  // end-of-kernel row-sum reduction (within each 32-lane half)
#pragma unroll
  for (int off = 1; off <= 16; off <<= 1)
#pragma unroll
    for (int r = 0; r < 16; r++)
      psum[r] += __shfl_xor(psum[r], off, 64);

#pragma unroll
  for (int nt = 0; nt < 4; nt++)
#pragma unroll
    for (int r = 0; r < 16; r++) {
      int row = q0 + wave * 32 + (r & 3) + 8 * (r >> 2) + 4 * half;
      ob[(long)row * HID + h * HD + nt * 32 + l31] = f2bf(oacc[nt][r] / psum[r]);
    }
}

extern "C" void kernel_launch(void* const* d_in, const int* in_sizes, int n_in,
                              void* d_out, int out_size, void* d_ws, size_t ws_size,
                              hipStream_t stream) {
  const float* x  = (const float*)d_in[0];
  const float* Wq = (const float*)d_in[1];
  const float* Wk = (const float*)d_in[2];
  const float* Wv = (const float*)d_in[3];
  const float* Wo = (const float*)d_in[4];
  float* out = (float*)d_out;

  char* ws = (char*)d_ws;
  size_t off = 0;
  auto alloc = [&](size_t bytes) {
    char* p = ws + off;
    off += (bytes + 255) & ~(size_t)255;
    return p;
  };
  unsigned short* x_bf    = (unsigned short*)alloc((size_t)T * HID * 2);
  unsigned short* wqkv_bf = (unsigned short*)alloc((size_t)6144 * HID * 2); // Wq++Wk++Wv; reused for Wo
  float* qkvf = (float*)alloc((size_t)T * 6144 * 4);                        // Q ++ K ++ V fused (fp32)
  unsigned short* qb  = (unsigned short*)alloc((size_t)NH * T * HD * 2);
  unsigned short* kbb = (unsigned short*)alloc((size_t)NKV * T * HD * 2);
  unsigned short* vtb = (unsigned short*)alloc((size_t)NKV * HD * T * 2);
  unsigned short* obb = (unsigned short*)alloc((size_t)T * HID * 2);

  // fused cast of x, Wq, Wk, Wv (one dispatch)
  int n0 = T * HID / 4, n1 = HID * HID / 4, n2 = 1024 * HID / 4, n3 = 1024 * HID / 4;
  int ntot = n0 + n1 + n2 + n3;
  cast4_kernel<<<dim3((ntot + 255) / 256), dim3(256), 0, stream>>>(
      x, Wq, Wk, Wv,
      x_bf, wqkv_bf, wqkv_bf + (size_t)HID * HID, wqkv_bf + (size_t)5120 * HID,
      n0, n1, n2, n3);

  // fused QKV projection: C[2048,6144] fp32 — 8-phase 256^2 GEMM (24x8 = 192 blocks)
  gemm8<<<dim3(6144 / 256, T / 256), dim3(512), 0, stream>>>(x_bf, wqkv_bf, qkvf, T, 6144, HID);

  rope_qk<<<dim3(T, NH + NKV), dim3(64), 0, stream>>>(qkvf, qb, kbb);
  transpose_v<<<dim3(T / 64, HD / 32, NKV), dim3(256), 0, stream>>>(qkvf, vtb);

  cast_bf16_kernel<<<dim3((HID * HID / 4 + 255) / 256), dim3(256), 0, stream>>>(Wo, wqkv_bf, HID * HID / 4);
  attn_kernel<<<dim3(T / 128, NH), dim3(256), 0, stream>>>(qb, kbb, vtb, obb);
  // output projection: 8-phase 256^2 GEMM (16x8 = 128 blocks)
  gemm8<<<dim3(HID / 256, T / 256), dim3(512), 0, stream>>>(obb, wqkv_bf, out, T, HID, HID);
}

// Round 2
// 459.315 us; speedup vs baseline: 1.1033x; 1.1033x over previous
//
#include <hip/hip_runtime.h>
#include <math.h>

#define T 2048
#define HID 4096
#define NH 32
#define NKV 8
#define HD 128
#define QSCALE 0.08838834764831845f   // 1/sqrt(128)

typedef __attribute__((ext_vector_type(8))) short short8;
typedef __attribute__((ext_vector_type(4))) float f32x4;
typedef __attribute__((ext_vector_type(16))) float f32x16;

static __device__ __forceinline__ unsigned short f2bf(float f) {
  union { float f; unsigned u; } v; v.f = f;
  unsigned r = v.u;
  r += 0x7fffu + ((r >> 16) & 1u);   // round-to-nearest-even
  return (unsigned short)(r >> 16);
}

// async 16B/lane global->LDS DMA; LDS dest is wave-uniform base + lane*16
static __device__ __forceinline__ void async_cp16(const unsigned short* g, unsigned short* l) {
  __builtin_amdgcn_global_load_lds(
      (const __attribute__((address_space(1))) void*)g,
      (__attribute__((address_space(3))) void*)l,
      16, 0, 0);
}

// ---------------- fused cast fp32 -> bf16 for x, Wq, Wk, Wv ----------------
__global__ __launch_bounds__(256) void cast4_kernel(const float* __restrict__ s0, const float* __restrict__ s1,
                                                    const float* __restrict__ s2, const float* __restrict__ s3,
                                                    unsigned short* __restrict__ d0, unsigned short* __restrict__ d1,
                                                    unsigned short* __restrict__ d2, unsigned short* __restrict__ d3,
                                                    int n0, int n1, int n2, int n3) {
  int i = blockIdx.x * 256 + threadIdx.x;
  const float* s; unsigned short* d; int j = i;
  if (j < n0) { s = s0; d = d0; }
  else { j -= n0;
    if (j < n1) { s = s1; d = d1; }
    else { j -= n1;
      if (j < n2) { s = s2; d = d2; }
      else { j -= n2;
        if (j >= n3) return;
        s = s3; d = d3; } } }
  float4 f = ((const float4*)s)[j];
  ushort4 o;
  o.x = f2bf(f.x); o.y = f2bf(f.y); o.z = f2bf(f.z); o.w = f2bf(f.w);
  ((ushort4*)d)[j] = o;
}

__global__ __launch_bounds__(256) void cast_bf16_kernel(const float* __restrict__ src,
                                                        unsigned short* __restrict__ dst,
                                                        int n4) {
  int i = blockIdx.x * 256 + threadIdx.x;
  if (i >= n4) return;
  float4 f = ((const float4*)src)[i];
  ushort4 o;
  o.x = f2bf(f.x); o.y = f2bf(f.y); o.z = f2bf(f.z); o.w = f2bf(f.w);
  ((ushort4*)dst)[i] = o;
}

// ---------------- 8-phase 256xBN GEMM (T2+T3+T4+T5 template, fill-exact grids) ----------------
// C[M,N] fp32 = A[M,K]bf16 * Bt[N,K]bf16^T.
// 512 threads = 8 waves (2M x 4N). BM=256, BN = NF*64 (NF=3: grid 32x8 for N=6144;
// NF=2: grid 32x8 for N=4096) -> exactly 256 blocks = full CU fill at 1 block/CU.
// BK=64, double-buffered LDS, stage granularity = 64 rows (one global_load_lds w16
// per wave), counted vmcnt (never 0 in the loop), swizzle slot ^= row&7 on both
// the pre-swizzled global source and the ds_read (round-1: conflicts == 0).

static __device__ __forceinline__ short8 ldfrag(const unsigned short* tile, int row0, int ks, int lane) {
  // row0 multiple of 16 so row&7 == lane&7
  int row = row0 + (lane & 15);
  int slot = (ks * 4 + (lane >> 4)) ^ (lane & 7);
  return *(const short8*)&tile[row * 64 + slot * 8];
}

// stage 64 rows x 64 cols (8KB) of G[grow0.., k0..k0+63] into lds (linear dest)
static __device__ __forceinline__ void stage64(const unsigned short* __restrict__ G, long grow0, int K, int k0,
                                               unsigned short* lds, int wave, int lane) {
  long row = grow0 + wave * 8 + (lane >> 3);
  int slot = (lane & 7) ^ (lane >> 3);       // inverse swizzle on the source
  async_cp16(&G[row * (long)K + k0 + slot * 8], &lds[wave * 512]);
}

template <int MQ>
static __device__ __forceinline__ void lda(short8 (&dst)[4][2], const unsigned short* tile, int ar, int lane) {
#pragma unroll
  for (int m = 0; m < 4; m++)
#pragma unroll
    for (int ks = 0; ks < 2; ks++)
      dst[m][ks] = ldfrag(tile, ar + MQ * 64 + m * 16, ks, lane);
}

template <int N0, int NN, int NF>
static __device__ __forceinline__ void ldb(short8 (&b)[NF][2], const unsigned short* tile, int br, int lane) {
#pragma unroll
  for (int n = 0; n < NN; n++)
#pragma unroll
    for (int ks = 0; ks < 2; ks++)
      b[N0 + n][ks] = ldfrag(tile, br + (N0 + n) * 16, ks, lane);
}

// ks OUTERMOST: dependent same-acc MFMA pairs are >=4*NN issues apart
template <int MQ, int N0, int NN, int NF>
static __device__ __forceinline__ void mfma_ph(const short8 (&af)[4][2], const short8 (&b)[NF][2],
                                               f32x4 (&acc)[8][NF]) {
  __builtin_amdgcn_s_setprio(1);
#pragma unroll
  for (int ks = 0; ks < 2; ks++)
#pragma unroll
    for (int m = 0; m < 4; m++)
#pragma unroll
      for (int n = 0; n < NN; n++)
        acc[MQ * 4 + m][N0 + n] = __builtin_amdgcn_mfma_f32_16x16x32_bf16(
            af[m][ks], b[N0 + n][ks], acc[MQ * 4 + m][N0 + n], 0, 0, 0);
  __builtin_amdgcn_s_setprio(0);
}

#define SCHED0 __builtin_amdgcn_sched_barrier(0)
#define BAR_PRE  do { SCHED0; __builtin_amdgcn_s_barrier(); \
                      asm volatile("s_waitcnt lgkmcnt(0)" ::: "memory"); SCHED0; } while (0)
#define BAR_POST do { SCHED0; __builtin_amdgcn_s_barrier(); SCHED0; } while (0)
#define VMCNT(n) asm volatile("s_waitcnt vmcnt(" #n ")" ::: "memory")

template <int NF>
__global__ __launch_bounds__(512, 2) void gemm8t(const unsigned short* __restrict__ A,
                                                 const unsigned short* __restrict__ Bt,
                                                 float* __restrict__ C,
                                                 int M, int N, int K) {
  constexpr int BN = NF * 64;
  __shared__ __align__(16) unsigned short As[2][16384];     // 2 x 256x64
  __shared__ __align__(16) unsigned short Bs[2][BN * 64];   // 2 x BNx64
  int tid = threadIdx.x, wave = tid >> 6, lane = tid & 63;
  int wm = wave >> 2, wn = wave & 3;
  long bm0 = (long)blockIdx.y * 256, bn0 = (long)blockIdx.x * BN;
  int ar = wm * 128, br = wn * (NF * 16);

  f32x4 acc[8][NF] = {};
  short8 a0[4][2], a1[4][2], b[NF][2];
  int nkt = K >> 6;

  if constexpr (NF == 3) {
    // prologue: B(t0)x3 -> Bs0, A(t0)x4 -> As0, B(t1)x3 -> Bs1; keep 3 in flight
#pragma unroll
    for (int c = 0; c < 3; c++) stage64(Bt, bn0 + c * 64, K, 0, &Bs[0][c * 4096], wave, lane);
#pragma unroll
    for (int c = 0; c < 4; c++) stage64(A, bm0 + c * 64, K, 0, &As[0][c * 4096], wave, lane);
#pragma unroll
    for (int c = 0; c < 3; c++) stage64(Bt, bn0 + c * 64, K, 64, &Bs[1][c * 4096], wave, lane);
    VMCNT(3);
    SCHED0; __builtin_amdgcn_s_barrier(); SCHED0;

#pragma unroll 1
    for (int it = 0; it < (nkt >> 1); ++it) {
      int k1 = (2 * it + 1) << 6;
      int t2 = 2 * it + 2; if (t2 > nkt - 1) t2 = nkt - 1;   // tail: stale restage (dead)
      int t3 = 2 * it + 3; if (t3 > nkt - 1) t3 = nkt - 1;
      int k2 = t2 << 6, k3 = t3 << 6;

      // Ph0: read a0,b01(buf0); stage A(k1) c0,c1 -> As1 (As1 reads done prev Ph6)
      lda<0>(a0, As[0], ar, lane); ldb<0, 2, NF>(b, Bs[0], br, lane);
      stage64(A, bm0 + 0, K, k1, &As[1][0], wave, lane);
      stage64(A, bm0 + 64, K, k1, &As[1][4096], wave, lane);
      BAR_PRE; mfma_ph<0, 0, 2>(a0, b, acc); BAR_POST;
      // Ph1: read b2(buf0); stage A(k1) c2,c3
      ldb<2, 1, NF>(b, Bs[0], br, lane);
      stage64(A, bm0 + 128, K, k1, &As[1][8192], wave, lane);
      stage64(A, bm0 + 192, K, k1, &As[1][12288], wave, lane);
      BAR_PRE; mfma_ph<0, 2, 1>(a0, b, acc); BAR_POST;
      // Ph2: read a1(buf0); stage B(k2) c0,c1 -> Bs0 (Bs0 reads done Ph1)
      lda<1>(a1, As[0], ar, lane);
      stage64(Bt, bn0 + 0, K, k2, &Bs[0][0], wave, lane);
      stage64(Bt, bn0 + 64, K, k2, &Bs[0][4096], wave, lane);
      BAR_PRE; mfma_ph<1, 0, 2>(a1, b, acc); BAR_POST;
      // Ph3: stage B(k2) c2; vmcnt(3) -> buf1 (B prev Ph6-7 + A Ph0-1) landed
      stage64(Bt, bn0 + 128, K, k2, &Bs[0][8192], wave, lane);
      VMCNT(3);
      BAR_PRE; mfma_ph<1, 2, 1>(a1, b, acc); BAR_POST;
      // Ph4: read a0,b01(buf1); stage A(k2) c0,c1 -> As0 (As0 reads done Ph2)
      lda<0>(a0, As[1], ar, lane); ldb<0, 2, NF>(b, Bs[1], br, lane);
      stage64(A, bm0 + 0, K, k2, &As[0][0], wave, lane);
      stage64(A, bm0 + 64, K, k2, &As[0][4096], wave, lane);
      BAR_PRE; mfma_ph<0, 0, 2>(a0, b, acc); BAR_POST;
      // Ph5: read b2(buf1); stage A(k2) c2,c3
      ldb<2, 1, NF>(b, Bs[1], br, lane);
      stage64(A, bm0 + 128, K, k2, &As[0][8192], wave, lane);
      stage64(A, bm0 + 192, K, k2, &As[0][12288], wave, lane);
      BAR_PRE; mfma_ph<0, 2, 1>(a0, b, acc); BAR_POST;
      // Ph6: read a1(buf1); stage B(k3) c0,c1 -> Bs1 (Bs1 reads done Ph5)
      lda<1>(a1, As[1], ar, lane);
      stage64(Bt, bn0 + 0, K, k3, &Bs[1][0], wave, lane);
      stage64(Bt, bn0 + 64, K, k3, &Bs[1][4096], wave, lane);
      BAR_PRE; mfma_ph<1, 0, 2>(a1, b, acc); BAR_POST;
      // Ph7: stage B(k3) c2; vmcnt(3) -> buf0 (B Ph2-3 + A Ph4-5) landed
      stage64(Bt, bn0 + 128, K, k3, &Bs[1][8192], wave, lane);
      VMCNT(3);
      BAR_PRE; mfma_ph<1, 2, 1>(a1, b, acc); BAR_POST;
    }
  } else {  // NF == 2: 4 phases / 2-K-tile iteration
#pragma unroll
    for (int c = 0; c < 2; c++) stage64(Bt, bn0 + c * 64, K, 0, &Bs[0][c * 4096], wave, lane);
#pragma unroll
    for (int c = 0; c < 4; c++) stage64(A, bm0 + c * 64, K, 0, &As[0][c * 4096], wave, lane);
#pragma unroll
    for (int c = 0; c < 2; c++) stage64(Bt, bn0 + c * 64, K, 64, &Bs[1][c * 4096], wave, lane);
    VMCNT(2);
    SCHED0; __builtin_amdgcn_s_barrier(); SCHED0;

#pragma unroll 1
    for (int it = 0; it < (nkt >> 1); ++it) {
      int k1 = (2 * it + 1) << 6;
      int t2 = 2 * it + 2; if (t2 > nkt - 1) t2 = nkt - 1;
      int t3 = 2 * it + 3; if (t3 > nkt - 1) t3 = nkt - 1;
      int k2 = t2 << 6, k3 = t3 << 6;

      // Ph0: read a0,b01(buf0); stage A(k1) x4 -> As1 (As1 reads done prev Ph3)
      lda<0>(a0, As[0], ar, lane); ldb<0, 2, NF>(b, Bs[0], br, lane);
#pragma unroll
      for (int c = 0; c < 4; c++) stage64(A, bm0 + c * 64, K, k1, &As[1][c * 4096], wave, lane);
      BAR_PRE; mfma_ph<0, 0, 2>(a0, b, acc); BAR_POST;
      // Ph1: read a1(buf0); stage B(k2) x2 -> Bs0 (Bs0 reads done Ph0); vmcnt(2) -> buf1 landed
      lda<1>(a1, As[0], ar, lane);
#pragma unroll
      for (int c = 0; c < 2; c++) stage64(Bt, bn0 + c * 64, K, k2, &Bs[0][c * 4096], wave, lane);
      VMCNT(2);
      BAR_PRE; mfma_ph<1, 0, 2>(a1, b, acc); BAR_POST;
      // Ph2: read a0,b01(buf1); stage A(k2) x4 -> As0 (As0 reads done Ph1)
      lda<0>(a0, As[1], ar, lane); ldb<0, 2, NF>(b, Bs[1], br, lane);
#pragma unroll
      for (int c = 0; c < 4; c++) stage64(A, bm0 + c * 64, K, k2, &As[0][c * 4096], wave, lane);
      BAR_PRE; mfma_ph<0, 0, 2>(a0, b, acc); BAR_POST;
      // Ph3: read a1(buf1); stage B(k3) x2 -> Bs1 (Bs1 reads done Ph2); vmcnt(2) -> buf0 landed
      lda<1>(a1, As[1], ar, lane);
#pragma unroll
      for (int c = 0; c < 2; c++) stage64(Bt, bn0 + c * 64, K, k3, &Bs[1][c * 4096], wave, lane);
      VMCNT(2);
      BAR_PRE; mfma_ph<1, 0, 2>(a1, b, acc); BAR_POST;
    }
  }
  VMCNT(0);   // drain tail stages before endpgm

  // epilogue: 16x16 C/D layout: col = lane&15, row = (lane>>4)*4 + j
#pragma unroll
  for (int m = 0; m < 8; m++)
#pragma unroll
    for (int n = 0; n < NF; n++) {
      long row = bm0 + ar + m * 16 + ((lane >> 4) << 2);
      long col = bn0 + br + n * 16 + (lane & 15);
#pragma unroll
      for (int j = 0; j < 4; j++)
        C[(row + j) * (long)N + col] = acc[m][n][j];
    }
}

// ---------------- RoPE (llama3 scaling) on Q,K from fused QKV; head-major bf16 ----------------
__global__ __launch_bounds__(64) void rope_qk(const float* __restrict__ qkvf,
                                              unsigned short* __restrict__ qb,
                                              unsigned short* __restrict__ kb) {
  int t = blockIdx.x, hh = blockIdx.y, d = threadIdx.x;  // d in [0,64)
  float ex = (float)d * (1.0f / 64.0f);
  float inv = expf(-ex * 13.122363377404328f);           // 500000^(-d/64)
  float wl = 6.283185307179586f / inv;
  float inv_s;
  if (wl > 8192.0f)       inv_s = inv * 0.125f;
  else if (wl < 2048.0f)  inv_s = inv;
  else {
    float smooth = (8192.0f / wl - 1.0f) * (1.0f / 3.0f);
    inv_s = (1.0f - smooth) * 0.125f * inv + smooth * inv;
  }
  float ang = (float)t * inv_s;
  float s, c;
  sincosf(ang, &s, &c);
  if (hh < NH) {
    const float* base = qkvf + (long)t * 6144 + hh * HD;
    float lo = base[d], hi = base[d + 64];
    long o = ((long)hh * T + t) * HD;
    qb[o + d]      = f2bf((lo * c - hi * s) * QSCALE);
    qb[o + d + 64] = f2bf((hi * c + lo * s) * QSCALE);
  } else {
    int h = hh - NH;
    const float* base = qkvf + (long)t * 6144 + 4096 + h * HD;
    float lo = base[d], hi = base[d + 64];
    long o = ((long)h * T + t) * HD;
    kb[o + d]      = f2bf(lo * c - hi * s);
    kb[o + d + 64] = f2bf(hi * c + lo * s);
  }
}

// ---------------- V: qkvf[t][5120 + h*128+d] fp32 -> [h][d][t] bf16 ----------------
__global__ __launch_bounds__(256) void transpose_v(const float* __restrict__ qkvf,
                                                   unsigned short* __restrict__ vtb) {
  __shared__ float tile[64][33];
  int t0 = blockIdx.x * 64, d0 = blockIdx.y * 32, h = blockIdx.z;
  int tid = threadIdx.x;
  int dd = tid & 31, tt = tid >> 5;
#pragma unroll
  for (int i = 0; i < 8; i++) {
    int t = tt + i * 8;
    tile[t][dd] = qkvf[(long)(t0 + t) * 6144 + 5120 + h * HD + d0 + dd];
  }
  __syncthreads();
  int t2 = tid & 63, d2 = tid >> 6;
#pragma unroll
  for (int i = 0; i < 8; i++) {
    int d = d2 + i * 4;
    vtb[((long)(h * HD + d0 + d)) * T + t0 + t2] = f2bf(tile[t2][d]);
  }
}

// ---------------- flash attention, causal, GQA (proven, unchanged) ----------------
__global__ __launch_bounds__(256, 2) void attn_kernel(const unsigned short* __restrict__ qb,
                                                      const unsigned short* __restrict__ kbuf,
                                                      const unsigned short* __restrict__ vtb,
                                                      unsigned short* __restrict__ ob) {
  __shared__ __align__(16) unsigned short Ks[64 * 128];   // [key][d], groups XOR row&15
  __shared__ __align__(16) unsigned short Vs[128 * 64];   // [d][key], groups XOR row&7
  __shared__ __align__(16) unsigned short Ps[4][32 * 76]; // per-wave P, stride 76
  int h = blockIdx.y;
  int kvh = h >> 2;
  // complementary causal workload pairing for co-resident blocks
  int qt = (blockIdx.y >= 16) ? (int)(gridDim.x - 1 - blockIdx.x) : (int)blockIdx.x;
  int q0 = qt * 128;
  int tid = threadIdx.x, wave = tid >> 6, lane = tid & 63;
  int l31 = lane & 31, half = lane >> 5;
  const unsigned short* Kb = kbuf + (long)kvh * T * HD;  // [t][d]
  const unsigned short* Vb = vtb + (long)kvh * HD * T;   // [d][t]

  // Q A-frags (32x32x16 layout: m=lane&31, k=half*8+j)
  int qrow = q0 + wave * 32 + l31;
  short8 aq[8];
#pragma unroll
  for (int ks = 0; ks < 8; ks++)
    aq[ks] = *(const short8*)&qb[((long)h * T + qrow) * HD + ks * 16 + half * 8];

  f32x16 oacc[4] = {};
  float psum[16];
#pragma unroll
  for (int r = 0; r < 16; r++) psum[r] = 0.0f;

  int ntiles = 2 * qt + 2;
  for (int tile = 0; tile < ntiles; tile++) {
    int kb0 = tile * 64;
#pragma unroll
    for (int i = 0; i < 4; i++) {
      int c = wave * 4 + i;
      { int row = c * 4 + (lane >> 4);
        int g = (lane & 15) ^ (row & 15);
        async_cp16(&Kb[(long)(kb0 + row) * HD + g * 8], &Ks[c * 512]); }
      { int row = c * 8 + (lane >> 3);
        int g = (lane & 7) ^ (row & 7);
        async_cp16(&Vb[(long)row * T + kb0 + g * 8], &Vs[c * 512]); }
    }
    __syncthreads();

    // S = Q K^T : 32q x 64key per wave
    f32x16 sacc[2] = {};
#pragma unroll
    for (int ks = 0; ks < 8; ks++)
#pragma unroll
      for (int nt = 0; nt < 2; nt++) {
        int row = nt * 32 + l31;
        short8 bk = *(const short8*)&Ks[row * 128 + (((2 * ks + half) ^ (row & 15)) * 8)];
        sacc[nt] = __builtin_amdgcn_mfma_f32_32x32x16_bf16(aq[ks], bk, sacc[nt], 0, 0, 0);
      }

    // causal mask (wave-uniform branch)
    if (kb0 + 63 > q0 + wave * 32) {
#pragma unroll
      for (int nt = 0; nt < 2; nt++) {
        int key = kb0 + nt * 32 + l31;
#pragma unroll
        for (int r = 0; r < 16; r++) {
          int qr = q0 + wave * 32 + (r & 3) + 8 * (r >> 2) + 4 * half;
          if (key > qr) sacc[nt][r] = -3.0e38f;
        }
      }
    }

    // p = exp(s); per-lane partial row sums; pack P to LDS
#pragma unroll
    for (int nt = 0; nt < 2; nt++)
#pragma unroll
      for (int r = 0; r < 16; r++) {
        float p = __expf(sacc[nt][r]);
        psum[r] += p;
        int prow = (r & 3) + 8 * (r >> 2) + 4 * half;
        Ps[wave][prow * 76 + nt * 32 + l31] = f2bf(p);
      }

    // O += P V
#pragma unroll
    for (int ks = 0; ks < 4; ks++) {
      short8 ap = *(const short8*)&Ps[wave][l31 * 76 + ks * 16 + half * 8];
#pragma unroll
      for (int nt = 0; nt < 4; nt++) {
        int row = nt * 32 + l31;
        short8 bv = *(const short8*)&Vs[row * 64 + (((2 * ks + half) ^ (row & 7)) * 8)];
        oacc[nt] = __builtin_amdgcn_mfma_f32_32x32x16_bf16(ap, bv, oacc[nt], 0, 0, 0);
      }
    }
    __syncthreads();
  }

  // end-of-kernel row-sum reduction (within each 32-lane half)
#pragma unroll
  for (int off = 1; off <= 16; off <<= 1)
#pragma unroll
    for (int r = 0; r < 16; r++)
      psum[r] += __shfl_xor(psum[r], off, 64);

#pragma unroll
  for (int nt = 0; nt < 4; nt++)
#pragma unroll
    for (int r = 0; r < 16; r++) {
      int row = q0 + wave * 32 + (r & 3) + 8 * (r >> 2) + 4 * half;
      ob[(long)row * HID + h * HD + nt * 32 + l31] = f2bf(oacc[nt][r] / psum[r]);
    }
}

extern "C" void kernel_launch(void* const* d_in, const int* in_sizes, int n_in,
                              void* d_out, int out_size, void* d_ws, size_t ws_size,
                              hipStream_t stream) {
  const float* x  = (const float*)d_in[0];
  const float* Wq = (const float*)d_in[1];
  const float* Wk = (const float*)d_in[2];
  const float* Wv = (const float*)d_in[3];
  const float* Wo = (const float*)d_in[4];
  float* out = (float*)d_out;

  char* ws = (char*)d_ws;
  size_t off = 0;
  auto alloc = [&](size_t bytes) {
    char* p = ws + off;
    off += (bytes + 255) & ~(size_t)255;
    return p;
  };
  unsigned short* x_bf    = (unsigned short*)alloc((size_t)T * HID * 2);
  unsigned short* wqkv_bf = (unsigned short*)alloc((size_t)6144 * HID * 2); // Wq++Wk++Wv; reused for Wo
  float* qkvf = (float*)alloc((size_t)T * 6144 * 4);                        // Q ++ K ++ V fused (fp32)
  unsigned short* qb  = (unsigned short*)alloc((size_t)NH * T * HD * 2);
  unsigned short* kbb = (unsigned short*)alloc((size_t)NKV * T * HD * 2);
  unsigned short* vtb = (unsigned short*)alloc((size_t)NKV * HD * T * 2);
  unsigned short* obb = (unsigned short*)alloc((size_t)T * HID * 2);

  // fused cast of x, Wq, Wk, Wv (one dispatch)
  int n0 = T * HID / 4, n1 = HID * HID / 4, n2 = 1024 * HID / 4, n3 = 1024 * HID / 4;
  int ntot = n0 + n1 + n2 + n3;
  cast4_kernel<<<dim3((ntot + 255) / 256), dim3(256), 0, stream>>>(
      x, Wq, Wk, Wv,
      x_bf, wqkv_bf, wqkv_bf + (size_t)HID * HID, wqkv_bf + (size_t)5120 * HID,
      n0, n1, n2, n3);

  // fused QKV projection: C[2048,6144] fp32 — BN=192, grid 32x8 = 256 blocks (full fill)
  gemm8t<3><<<dim3(6144 / 192, T / 256), dim3(512), 0, stream>>>(x_bf, wqkv_bf, qkvf, T, 6144, HID);

  rope_qk<<<dim3(T, NH + NKV), dim3(64), 0, stream>>>(qkvf, qb, kbb);
  transpose_v<<<dim3(T / 64, HD / 32, NKV), dim3(256), 0, stream>>>(qkvf, vtb);

  cast_bf16_kernel<<<dim3((HID * HID / 4 + 255) / 256), dim3(256), 0, stream>>>(Wo, wqkv_bf, HID * HID / 4);
  attn_kernel<<<dim3(T / 128, NH), dim3(256), 0, stream>>>(qb, kbb, vtb, obb);
  // output projection: BN=128, grid 32x8 = 256 blocks (full fill)
  gemm8t<2><<<dim3(HID / 128, T / 256), dim3(512), 0, stream>>>(obb, wqkv_bf, out, T, HID, HID);
}